// Round 5
// baseline (2064.524 us; speedup 1.0000x reference)
//
#include <hip/hip_runtime.h>
#include <math.h>

#define TT 1024
#define DD 128
#define UU 64

typedef __attribute__((ext_vector_type(64))) float f32x64;

__device__ __forceinline__ float sigm(float x) {
    return __builtin_amdgcn_rcpf(1.0f + __expf(-x));
}
__device__ __forceinline__ float tanhfast(float x) {
    float e = __expf(2.0f * x);
    return fmaf(-2.0f, __builtin_amdgcn_rcpf(e + 1.0f), 1.0f);
}

// DPP-based full-wave (64-lane) sum, result broadcast via readlane(63).
template<int CTRL>
__device__ __forceinline__ float dpp_add(float v) {
    return v + __int_as_float(__builtin_amdgcn_update_dpp(
        0, __float_as_int(v), CTRL, 0xf, 0xf, true));
}
__device__ __forceinline__ float wave_red_sum(float v) {
    v = dpp_add<0x111>(v);   // row_shr:1
    v = dpp_add<0x112>(v);   // row_shr:2
    v = dpp_add<0x114>(v);   // row_shr:4
    v = dpp_add<0x118>(v);   // row_shr:8
    v = dpp_add<0x142>(v);   // row_bcast:15
    v = dpp_add<0x143>(v);   // row_bcast:31
    return __int_as_float(__builtin_amdgcn_readlane(__float_as_int(v), 63));
}

// 64-float dot: LDS vector (broadcast reads) x register-resident weights.
__device__ __forceinline__ float dot64v(const float* v, f32x64 w) {
    const float4* v4 = (const float4*)v;
    float a0 = 0.f, a1 = 0.f, a2 = 0.f, a3 = 0.f;
    #pragma unroll
    for (int k4 = 0; k4 < UU / 4; ++k4) {
        float4 hv = v4[k4];
        a0 = fmaf(hv.x, w[4 * k4 + 0], a0);
        a1 = fmaf(hv.y, w[4 * k4 + 1], a1);
        a2 = fmaf(hv.z, w[4 * k4 + 2], a2);
        a3 = fmaf(hv.w, w[4 * k4 + 3], a3);
    }
    return (a0 + a1) + (a2 + a3);
}

// ================= x-part GEMM: z1x[r, col] = obss[b, t0+tloc, :] @ W1[0:128, col]
__global__ __launch_bounds__(256, 1)
void xgemm(const float* __restrict__ obss, const float* __restrict__ W1,
           float* __restrict__ z1x, int t0, int chsh)
{
    const int tid = threadIdx.x;
    const int CH = 1 << chsh;
    __shared__ __align__(16) float xs[64 * DD];

    const int rbase = blockIdx.x * 64;
    for (int i = tid; i < 64 * (DD / 4); i += 256) {
        int rr = i >> 5;
        int k4 = i & 31;
        int r  = rbase + rr;
        int b  = r >> chsh;
        int tl = r & (CH - 1);
        ((float4*)xs)[rr * 32 + k4] =
            ((const float4*)(obss + ((size_t)b * TT + t0 + tl) * DD))[k4];
    }

    f32x64 wlo, whi;
    #pragma unroll
    for (int k = 0; k < UU; ++k) wlo[k] = W1[k * 256 + tid];
    #pragma unroll
    for (int k = 0; k < UU; ++k) whi[k] = W1[(UU + k) * 256 + tid];
    __syncthreads();

    for (int rr = 0; rr < 64; ++rr) {
        const float* x0 = xs + rr * DD;
        float a = dot64v(x0, wlo);
        float b = dot64v(x0 + UU, whi);
        z1x[((size_t)rbase + rr) * 256 + tid] = a + b;
    }
}

// ================= recurrent kernel: layer-pipelined, 512 threads ============
// Waves 0-3 (gid 0): layer 1 at step n; also compute z2x = h1 @ W2x in phase 2.
// Waves 4-7 (gid 1): layer 2 at step n-1; z2h = h2 @ W2h computed in phase 2
// (carried in a register), so phase 1 is just add+LN+act. 2 barriers/step.
__global__ __launch_bounds__(512, 2)
void lstm_rec(const float* __restrict__ z1x,
              const float* __restrict__ W1, const float* __restrict__ W2,
              const float* __restrict__ gamma1, const float* __restrict__ beta1,
              const float* __restrict__ gc1, const float* __restrict__ bc1,
              const float* __restrict__ gamma2, const float* __restrict__ beta2,
              const float* __restrict__ gc2, const float* __restrict__ bc2,
              const float* __restrict__ Wd, const float* __restrict__ bd,
              float* __restrict__ out, float* __restrict__ state,
              int t0, int nsteps)
{
    const int tid  = threadIdx.x;
    const int b    = blockIdx.x;
    const int gid  = tid >> 8;        // 0 = layer-1 group, 1 = layer-2 group
    const int stid = tid & 255;
    const int lane = stid & 63;
    const int wav  = stid >> 6;

    __shared__ __align__(16) float zsA[256], zsB[256], z2xs[256];
    __shared__ __align__(16) float h1p[4][UU], h2p[4][UU];
    __shared__ __align__(16) float h2hist[16 * 65];
    __shared__ __align__(16) float wds[UU * 16];
    __shared__ float bds[16];

    float* st = state + (size_t)b * 256;

    if (gid == 0) {
        // =========================== LAYER 1 (+ z2x feed) ===================
        f32x64 w1h, w2x;
        #pragma unroll
        for (int k = 0; k < UU; ++k) w1h[k] = W1[(DD + k) * 256 + stid];
        #pragma unroll
        for (int k = 0; k < UU; ++k) w2x[k] = W2[k * 256 + stid];
        const float g1 = gamma1[stid], bb1 = beta1[stid];
        const float gcl = gc1[lane],  bcl = bc1[lane];
        for (int i = stid; i < UU * 16; i += 256) wds[i] = Wd[i];
        if (stid < 16) bds[stid] = bd[stid];

        float c1, h1v = 0.f;
        if (t0 == 0) { c1 = 0.f; h1p[wav][lane] = 0.f; }
        else         { c1 = st[lane]; h1v = st[64 + lane]; h1p[wav][lane] = h1v; }

        const float* zrow = z1x + (size_t)b * nsteps * 256;
        float zx = zrow[stid];
        __syncthreads();                       // (init)

        #pragma unroll 1
        for (int n = 0; n <= nsteps; ++n) {
            float zxn = zx;
            if (n < nsteps) {
                int tnl = (n + 1 < nsteps) ? n + 1 : n;
                zxn = zrow[(size_t)tnl * 256 + stid];

                float z = zx + dot64v(h1p[wav], w1h);
                float s = wave_red_sum(z);
                float q = wave_red_sum(z * z);
                float mu  = s * (1.f/64.f);
                float var = q * (1.f/64.f) - mu * mu;
                float zn  = (z - mu) * __builtin_amdgcn_rsqf(var + 1e-12f) * g1 + bb1;
                zsA[stid] = (wav == 1) ? tanhfast(zn)
                          : (wav == 2) ? sigm(zn + 1.f)
                          :              sigm(zn);
            }
            // batched output projection for rows t2p-15..t2p (t2p = n-2)
            if ((n & 15) == 1 && n >= 17) {
                int t2p  = n - 2;
                int rloc = stid >> 4;
                int a    = stid & 15;
                float o = bds[a];
                #pragma unroll
                for (int k = 0; k < UU; ++k)
                    o = fmaf(h2hist[rloc * 65 + k], wds[k * 16 + a], o);
                int r = t0 + t2p - 15 + rloc;
                out[((size_t)b * TT + r) * 16 + a] = tanhfast(o);
            }
            __syncthreads();                   // B1
            if (n < nsteps) {
                float ai = zsA[lane],       aj = zsA[64 + lane];
                float af = zsA[128 + lane], ao = zsA[192 + lane];
                c1 = c1 * af + ai * aj;
                float cs = wave_red_sum(c1);
                float cq = wave_red_sum(c1 * c1);
                float cmu  = cs * (1.f/64.f);
                float cvar = cq * (1.f/64.f) - cmu * cmu;
                float cn   = (c1 - cmu) * __builtin_amdgcn_rsqf(cvar + 1e-12f) * gcl + bcl;
                h1v = tanhfast(cn) * ao;
                h1p[wav][lane] = h1v;
                // z2x = h1(n) @ W2x  (own-wave LDS write -> read, no barrier)
                z2xs[stid] = dot64v(h1p[wav], w2x);
            }
            __syncthreads();                   // B2
            zx = zxn;
        }
        // final projection: rows nsteps-16..nsteps-1
        {
            int rloc = stid >> 4;
            int a    = stid & 15;
            float o = bds[a];
            #pragma unroll
            for (int k = 0; k < UU; ++k)
                o = fmaf(h2hist[rloc * 65 + k], wds[k * 16 + a], o);
            int r = t0 + nsteps - 16 + rloc;
            out[((size_t)b * TT + r) * 16 + a] = tanhfast(o);
        }
        if (t0 + nsteps < TT && wav == 0) {
            st[lane]      = c1;
            st[64 + lane] = h1v;
        }
    } else {
        // =========================== LAYER 2 ===========================
        f32x64 w2h;
        #pragma unroll
        for (int k = 0; k < UU; ++k) w2h[k] = W2[(UU + k) * 256 + stid];
        const float g2 = gamma2[stid], bb2 = beta2[stid];
        const float gcl = gc2[lane],  bcl = bc2[lane];

        float c2, h2v = 0.f;
        if (t0 == 0) { c2 = 0.f; h2p[wav][lane] = 0.f; }
        else         { c2 = st[128 + lane]; h2v = st[192 + lane]; h2p[wav][lane] = h2v; }
        // z2h carried in-register: h2(prev) @ W2h (recomputed at chunk start)
        float z2h = (t0 == 0) ? 0.f : dot64v(h2p[wav], w2h);
        __syncthreads();                       // (init)

        #pragma unroll 1
        for (int n = 0; n <= nsteps; ++n) {
            if (n >= 1) {
                float z2 = z2xs[stid] + z2h;
                float s2 = wave_red_sum(z2);
                float q2 = wave_red_sum(z2 * z2);
                float mu2  = s2 * (1.f/64.f);
                float var2 = q2 * (1.f/64.f) - mu2 * mu2;
                float zn2  = (z2 - mu2) * __builtin_amdgcn_rsqf(var2 + 1e-12f) * g2 + bb2;
                zsB[stid] = (wav == 1) ? tanhfast(zn2)
                          : (wav == 2) ? sigm(zn2 + 1.f)
                          :              sigm(zn2);
            }
            __syncthreads();                   // B1
            if (n >= 1) {
                float ai = zsB[lane],       aj = zsB[64 + lane];
                float af = zsB[128 + lane], ao = zsB[192 + lane];
                c2 = c2 * af + ai * aj;
                float cs = wave_red_sum(c2);
                float cq = wave_red_sum(c2 * c2);
                float cmu  = cs * (1.f/64.f);
                float cvar = cq * (1.f/64.f) - cmu * cmu;
                float cn   = (c2 - cmu) * __builtin_amdgcn_rsqf(cvar + 1e-12f) * gcl + bcl;
                h2v = tanhfast(cn) * ao;
                h2p[wav][lane] = h2v;
                if (wav == 0) h2hist[((n - 1) & 15) * 65 + lane] = h2v;
                // z2h = h2(n-1) @ W2h for next step (own-wave write->read)
                z2h = dot64v(h2p[wav], w2h);
            }
            __syncthreads();                   // B2
        }
        if (t0 + nsteps < TT && wav == 0) {
            st[128 + lane] = c2;
            st[192 + lane] = h2v;
        }
    }
}

extern "C" void kernel_launch(void* const* d_in, const int* in_sizes, int n_in,
                              void* d_out, int out_size, void* d_ws, size_t ws_size,
                              hipStream_t stream) {
    (void)in_sizes; (void)n_in; (void)out_size;
    const float* obss   = (const float*)d_in[0];
    const float* W1     = (const float*)d_in[1];
    const float* gamma1 = (const float*)d_in[2];
    const float* beta1  = (const float*)d_in[3];
    const float* gc1    = (const float*)d_in[4];
    const float* bc1    = (const float*)d_in[5];
    const float* W2     = (const float*)d_in[6];
    const float* gamma2 = (const float*)d_in[7];
    const float* beta2  = (const float*)d_in[8];
    const float* gc2    = (const float*)d_in[9];
    const float* bc2    = (const float*)d_in[10];
    const float* Wd     = (const float*)d_in[11];
    const float* bd     = (const float*)d_in[12];
    float* out = (float*)d_out;

    float* state = (float*)d_ws;
    float* z1x   = (float*)((char*)d_ws + (size_t)256 * 256 * sizeof(float));

    int CH = 16;
    for (int c = TT; c >= 16; c >>= 1) {
        size_t need = (size_t)256 * c * 256 * sizeof(float)
                    + (size_t)256 * 256 * sizeof(float);
        if (need <= ws_size) { CH = c; break; }
    }
    int chsh = 31 - __builtin_clz((unsigned)CH);

    for (int t0 = 0; t0 < TT; t0 += CH) {
        xgemm<<<(256 * CH) / 64, 256, 0, stream>>>(obss, W1, z1x, t0, chsh);
        lstm_rec<<<256, 512, 0, stream>>>(z1x, W1, W2,
                                          gamma1, beta1, gc1, bc1,
                                          gamma2, beta2, gc2, bc2,
                                          Wd, bd, out, state, t0, CH);
    }
}

// Round 7
// 1462.430 us; speedup vs baseline: 1.4117x; 1.4117x over previous
//
#include <hip/hip_runtime.h>
#include <math.h>

#define TT 1024
#define DD 128
#define UU 64

__device__ __forceinline__ float sigm(float x) {
    return __builtin_amdgcn_rcpf(1.0f + __expf(-x));
}
__device__ __forceinline__ float tanhfast(float x) {
    float e = __expf(2.0f * x);
    return fmaf(-2.0f, __builtin_amdgcn_rcpf(e + 1.0f), 1.0f);
}

// DPP-based full-wave (64-lane) sum, result broadcast via readlane(63).
template<int CTRL>
__device__ __forceinline__ float dpp_add(float v) {
    return v + __int_as_float(__builtin_amdgcn_update_dpp(
        0, __float_as_int(v), CTRL, 0xf, 0xf, true));
}
__device__ __forceinline__ float wave_red_sum(float v) {
    v = dpp_add<0x111>(v);   // row_shr:1
    v = dpp_add<0x112>(v);   // row_shr:2
    v = dpp_add<0x114>(v);   // row_shr:4
    v = dpp_add<0x118>(v);   // row_shr:8
    v = dpp_add<0x142>(v);   // row_bcast:15
    v = dpp_add<0x143>(v);   // row_bcast:31
    return __int_as_float(__builtin_amdgcn_readlane(__float_as_int(v), 63));
}

// 64-float dot: LDS vector (broadcast reads) x register-resident weight ARRAY.
// Macro (not a function): indexes the named array with unroll-constant indices
// so SROA promotes the weights to scalar VGPRs (no pointer, no big vector).
// NOTE: parameter is WARR, not "w" -- a parameter named "w" would collide with
// the .w member-access token of float4 during preprocessing (round-6 bug).
#define DOT64(res, vptr, WARR) do {                                \
    const float4* _v4 = (const float4*)(vptr);                     \
    float _a0 = 0.f, _a1 = 0.f, _a2 = 0.f, _a3 = 0.f;              \
    _Pragma("unroll")                                              \
    for (int _k = 0; _k < UU / 4; ++_k) {                          \
        float4 _hv = _v4[_k];                                      \
        _a0 = fmaf(_hv.x, WARR[4 * _k + 0], _a0);                  \
        _a1 = fmaf(_hv.y, WARR[4 * _k + 1], _a1);                  \
        _a2 = fmaf(_hv.z, WARR[4 * _k + 2], _a2);                  \
        _a3 = fmaf(_hv.w, WARR[4 * _k + 3], _a3);                  \
    }                                                              \
    res = (_a0 + _a1) + (_a2 + _a3);                               \
} while (0)

// ================= x-part GEMM (round-4 proven version) ======================
// z1x[r, col] = obss[b, t0+tloc, :] @ W1[0:128, col]
__global__ __launch_bounds__(256, 1)
void xgemm(const float* __restrict__ obss, const float* __restrict__ W1,
           float* __restrict__ z1x, int t0, int chsh)
{
    const int tid = threadIdx.x;
    const int CH = 1 << chsh;
    __shared__ __align__(16) float xs[64 * DD];

    const int rbase = blockIdx.x * 64;
    for (int i = tid; i < 64 * (DD / 4); i += 256) {
        int rr = i >> 5;
        int k4 = i & 31;
        int r  = rbase + rr;
        int b  = r >> chsh;
        int tl = r & (CH - 1);
        ((float4*)xs)[rr * 32 + k4] =
            ((const float4*)(obss + ((size_t)b * TT + t0 + tl) * DD))[k4];
    }

    float w[DD];
    #pragma unroll
    for (int k = 0; k < DD; ++k) w[k] = W1[k * 256 + tid];
    __syncthreads();

    for (int rr = 0; rr < 64; rr += 2) {
        float a0=0,a1=0,a2=0,a3=0, b0=0,b1=0,b2=0,b3=0;
        const float4* x0 = (const float4*)(xs + rr * DD);
        const float4* x1 = (const float4*)(xs + (rr + 1) * DD);
        #pragma unroll
        for (int k4 = 0; k4 < DD / 4; ++k4) {
            float4 xv = x0[k4], yv = x1[k4];
            a0 = fmaf(xv.x, w[4*k4+0], a0);
            a1 = fmaf(xv.y, w[4*k4+1], a1);
            a2 = fmaf(xv.z, w[4*k4+2], a2);
            a3 = fmaf(xv.w, w[4*k4+3], a3);
            b0 = fmaf(yv.x, w[4*k4+0], b0);
            b1 = fmaf(yv.y, w[4*k4+1], b1);
            b2 = fmaf(yv.z, w[4*k4+2], b2);
            b3 = fmaf(yv.w, w[4*k4+3], b3);
        }
        size_t r = (size_t)rbase + rr;
        z1x[r * 256 + tid]       = (a0 + a1) + (a2 + a3);
        z1x[(r + 1) * 256 + tid] = (b0 + b1) + (b2 + b3);
    }
}

// ================= recurrent kernel: layer-pipelined, 512 threads ============
// Waves 0-3 (gid 0): layer 1 at step n; also compute z2x = h1 @ W2x in phase 2.
// Waves 4-7 (gid 1): layer 2 at step n-1; z2h = h2 @ W2h computed in phase 2
// (carried in a register), so phase 1 is just add+LN+act. 2 barriers/step.
__global__ __launch_bounds__(512, 2)
void lstm_rec(const float* __restrict__ z1x,
              const float* __restrict__ W1, const float* __restrict__ W2,
              const float* __restrict__ gamma1, const float* __restrict__ beta1,
              const float* __restrict__ gc1, const float* __restrict__ bc1,
              const float* __restrict__ gamma2, const float* __restrict__ beta2,
              const float* __restrict__ gc2, const float* __restrict__ bc2,
              const float* __restrict__ Wd, const float* __restrict__ bd,
              float* __restrict__ out, float* __restrict__ state,
              int t0, int nsteps)
{
    const int tid  = threadIdx.x;
    const int b    = blockIdx.x;
    const int gid  = tid >> 8;        // 0 = layer-1 group, 1 = layer-2 group
    const int stid = tid & 255;
    const int lane = stid & 63;
    const int wav  = stid >> 6;

    __shared__ __align__(16) float zsA[256], zsB[256], z2xs[256];
    __shared__ __align__(16) float h1p[4][UU], h2p[4][UU];
    __shared__ __align__(16) float h2hist[16 * 65];
    __shared__ __align__(16) float wds[UU * 16];
    __shared__ float bds[16];

    float* st = state + (size_t)b * 256;

    if (gid == 0) {
        // =========================== LAYER 1 (+ z2x feed) ===================
        float w1h[UU], w2x[UU];
        #pragma unroll
        for (int k = 0; k < UU; ++k) w1h[k] = W1[(DD + k) * 256 + stid];
        #pragma unroll
        for (int k = 0; k < UU; ++k) w2x[k] = W2[k * 256 + stid];
        const float g1 = gamma1[stid], bb1 = beta1[stid];
        const float gcl = gc1[lane],  bcl = bc1[lane];
        for (int i = stid; i < UU * 16; i += 256) wds[i] = Wd[i];
        if (stid < 16) bds[stid] = bd[stid];

        float c1, h1v = 0.f;
        if (t0 == 0) { c1 = 0.f; h1p[wav][lane] = 0.f; }
        else         { c1 = st[lane]; h1v = st[64 + lane]; h1p[wav][lane] = h1v; }

        const float* zrow = z1x + (size_t)b * nsteps * 256;
        float zx = zrow[stid];
        __syncthreads();                       // (init)

        #pragma unroll 1
        for (int n = 0; n <= nsteps; ++n) {
            float zxn = zx;
            if (n < nsteps) {
                int tnl = (n + 1 < nsteps) ? n + 1 : n;
                zxn = zrow[(size_t)tnl * 256 + stid];

                float zdot;
                DOT64(zdot, h1p[wav], w1h);
                float z = zx + zdot;
                float s = wave_red_sum(z);
                float q = wave_red_sum(z * z);
                float mu  = s * (1.f/64.f);
                float var = q * (1.f/64.f) - mu * mu;
                float zn  = (z - mu) * __builtin_amdgcn_rsqf(var + 1e-12f) * g1 + bb1;
                zsA[stid] = (wav == 1) ? tanhfast(zn)
                          : (wav == 2) ? sigm(zn + 1.f)
                          :              sigm(zn);
            }
            // batched output projection for rows t2p-15..t2p (t2p = n-2)
            if ((n & 15) == 1 && n >= 17) {
                int t2p  = n - 2;
                int rloc = stid >> 4;
                int a    = stid & 15;
                float o = bds[a];
                #pragma unroll
                for (int k = 0; k < UU; ++k)
                    o = fmaf(h2hist[rloc * 65 + k], wds[k * 16 + a], o);
                int r = t0 + t2p - 15 + rloc;
                out[((size_t)b * TT + r) * 16 + a] = tanhfast(o);
            }
            __syncthreads();                   // B1
            if (n < nsteps) {
                float ai = zsA[lane],       aj = zsA[64 + lane];
                float af = zsA[128 + lane], ao = zsA[192 + lane];
                c1 = c1 * af + ai * aj;
                float cs = wave_red_sum(c1);
                float cq = wave_red_sum(c1 * c1);
                float cmu  = cs * (1.f/64.f);
                float cvar = cq * (1.f/64.f) - cmu * cmu;
                float cn   = (c1 - cmu) * __builtin_amdgcn_rsqf(cvar + 1e-12f) * gcl + bcl;
                h1v = tanhfast(cn) * ao;
                h1p[wav][lane] = h1v;
                // z2x = h1(n) @ W2x  (own-wave LDS write -> read, no barrier)
                float zxdot;
                DOT64(zxdot, h1p[wav], w2x);
                z2xs[stid] = zxdot;
            }
            __syncthreads();                   // B2
            zx = zxn;
        }
        // final projection: rows nsteps-16..nsteps-1
        {
            int rloc = stid >> 4;
            int a    = stid & 15;
            float o = bds[a];
            #pragma unroll
            for (int k = 0; k < UU; ++k)
                o = fmaf(h2hist[rloc * 65 + k], wds[k * 16 + a], o);
            int r = t0 + nsteps - 16 + rloc;
            out[((size_t)b * TT + r) * 16 + a] = tanhfast(o);
        }
        if (t0 + nsteps < TT && wav == 0) {
            st[lane]      = c1;
            st[64 + lane] = h1v;
        }
    } else {
        // =========================== LAYER 2 ===========================
        float w2h[UU];
        #pragma unroll
        for (int k = 0; k < UU; ++k) w2h[k] = W2[(UU + k) * 256 + stid];
        const float g2 = gamma2[stid], bb2 = beta2[stid];
        const float gcl = gc2[lane],  bcl = bc2[lane];

        float c2, h2v = 0.f;
        if (t0 == 0) { c2 = 0.f; h2p[wav][lane] = 0.f; }
        else         { c2 = st[128 + lane]; h2v = st[192 + lane]; h2p[wav][lane] = h2v; }
        // z2h carried in-register: h2(prev) @ W2h (recomputed at chunk start)
        float z2h = 0.f;
        if (t0 != 0) { DOT64(z2h, h2p[wav], w2h); }
        __syncthreads();                       // (init)

        #pragma unroll 1
        for (int n = 0; n <= nsteps; ++n) {
            if (n >= 1) {
                float z2 = z2xs[stid] + z2h;
                float s2 = wave_red_sum(z2);
                float q2 = wave_red_sum(z2 * z2);
                float mu2  = s2 * (1.f/64.f);
                float var2 = q2 * (1.f/64.f) - mu2 * mu2;
                float zn2  = (z2 - mu2) * __builtin_amdgcn_rsqf(var2 + 1e-12f) * g2 + bb2;
                zsB[stid] = (wav == 1) ? tanhfast(zn2)
                          : (wav == 2) ? sigm(zn2 + 1.f)
                          :              sigm(zn2);
            }
            __syncthreads();                   // B1
            if (n >= 1) {
                float ai = zsB[lane],       aj = zsB[64 + lane];
                float af = zsB[128 + lane], ao = zsB[192 + lane];
                c2 = c2 * af + ai * aj;
                float cs = wave_red_sum(c2);
                float cq = wave_red_sum(c2 * c2);
                float cmu  = cs * (1.f/64.f);
                float cvar = cq * (1.f/64.f) - cmu * cmu;
                float cn   = (c2 - cmu) * __builtin_amdgcn_rsqf(cvar + 1e-12f) * gcl + bcl;
                h2v = tanhfast(cn) * ao;
                h2p[wav][lane] = h2v;
                if (wav == 0) h2hist[((n - 1) & 15) * 65 + lane] = h2v;
                // z2h = h2(n-1) @ W2h for next step (own-wave write->read)
                DOT64(z2h, h2p[wav], w2h);
            }
            __syncthreads();                   // B2
        }
        if (t0 + nsteps < TT && wav == 0) {
            st[128 + lane] = c2;
            st[192 + lane] = h2v;
        }
    }
}

extern "C" void kernel_launch(void* const* d_in, const int* in_sizes, int n_in,
                              void* d_out, int out_size, void* d_ws, size_t ws_size,
                              hipStream_t stream) {
    (void)in_sizes; (void)n_in; (void)out_size;
    const float* obss   = (const float*)d_in[0];
    const float* W1     = (const float*)d_in[1];
    const float* gamma1 = (const float*)d_in[2];
    const float* beta1  = (const float*)d_in[3];
    const float* gc1    = (const float*)d_in[4];
    const float* bc1    = (const float*)d_in[5];
    const float* W2     = (const float*)d_in[6];
    const float* gamma2 = (const float*)d_in[7];
    const float* beta2  = (const float*)d_in[8];
    const float* gc2    = (const float*)d_in[9];
    const float* bc2    = (const float*)d_in[10];
    const float* Wd     = (const float*)d_in[11];
    const float* bd     = (const float*)d_in[12];
    float* out = (float*)d_out;

    float* state = (float*)d_ws;
    float* z1x   = (float*)((char*)d_ws + (size_t)256 * 256 * sizeof(float));

    int CH = 16;
    for (int c = TT; c >= 16; c >>= 1) {
        size_t need = (size_t)256 * c * 256 * sizeof(float)
                    + (size_t)256 * 256 * sizeof(float);
        if (need <= ws_size) { CH = c; break; }
    }
    int chsh = 31 - __builtin_clz((unsigned)CH);

    for (int t0 = 0; t0 < TT; t0 += CH) {
        xgemm<<<(256 * CH) / 64, 256, 0, stream>>>(obss, W1, z1x, t0, chsh);
        lstm_rec<<<256, 512, 0, stream>>>(z1x, W1, W2,
                                          gamma1, beta1, gc1, bc1,
                                          gamma2, beta2, gc2, bc2,
                                          Wd, bd, out, state, t0, CH);
    }
}

// Round 8
// 1459.244 us; speedup vs baseline: 1.4148x; 1.0022x over previous
//
#include <hip/hip_runtime.h>
#include <math.h>

#define TT 1024
#define DD 128
#define UU 64

__device__ __forceinline__ float sigm(float x) {
    return __builtin_amdgcn_rcpf(1.0f + __expf(-x));
}
__device__ __forceinline__ float tanhfast(float x) {
    float e = __expf(2.0f * x);
    return fmaf(-2.0f, __builtin_amdgcn_rcpf(e + 1.0f), 1.0f);
}

// DPP-based full-wave (64-lane) sum, result broadcast via readlane(63).
template<int CTRL>
__device__ __forceinline__ float dpp_add(float v) {
    return v + __int_as_float(__builtin_amdgcn_update_dpp(
        0, __float_as_int(v), CTRL, 0xf, 0xf, true));
}
__device__ __forceinline__ float wave_red_sum(float v) {
    v = dpp_add<0x111>(v);   // row_shr:1
    v = dpp_add<0x112>(v);   // row_shr:2
    v = dpp_add<0x114>(v);   // row_shr:4
    v = dpp_add<0x118>(v);   // row_shr:8
    v = dpp_add<0x142>(v);   // row_bcast:15
    v = dpp_add<0x143>(v);   // row_bcast:31
    return __int_as_float(__builtin_amdgcn_readlane(__float_as_int(v), 63));
}

// 64-float dot: LDS vector (broadcast reads) x register-resident weight ARRAY.
#define DOT64(res, vptr, WARR) do {                                \
    const float4* _v4 = (const float4*)(vptr);                     \
    float _a0 = 0.f, _a1 = 0.f, _a2 = 0.f, _a3 = 0.f;              \
    _Pragma("unroll")                                              \
    for (int _k = 0; _k < UU / 4; ++_k) {                          \
        float4 _hv = _v4[_k];                                      \
        _a0 = fmaf(_hv.x, WARR[4 * _k + 0], _a0);                  \
        _a1 = fmaf(_hv.y, WARR[4 * _k + 1], _a1);                  \
        _a2 = fmaf(_hv.z, WARR[4 * _k + 2], _a2);                  \
        _a3 = fmaf(_hv.w, WARR[4 * _k + 3], _a3);                  \
    }                                                              \
    res = (_a0 + _a1) + (_a2 + _a3);                               \
} while (0)

// ================= x-part GEMM (round-4 proven version) ======================
// z1x[r, col] = obss[b, t0+tloc, :] @ W1[0:128, col]
__global__ __launch_bounds__(256, 1)
void xgemm(const float* __restrict__ obss, const float* __restrict__ W1,
           float* __restrict__ z1x, int t0, int chsh)
{
    const int tid = threadIdx.x;
    const int CH = 1 << chsh;
    __shared__ __align__(16) float xs[64 * DD];

    const int rbase = blockIdx.x * 64;
    for (int i = tid; i < 64 * (DD / 4); i += 256) {
        int rr = i >> 5;
        int k4 = i & 31;
        int r  = rbase + rr;
        int b  = r >> chsh;
        int tl = r & (CH - 1);
        ((float4*)xs)[rr * 32 + k4] =
            ((const float4*)(obss + ((size_t)b * TT + t0 + tl) * DD))[k4];
    }

    float w[DD];
    #pragma unroll
    for (int k = 0; k < DD; ++k) w[k] = W1[k * 256 + tid];
    __syncthreads();

    for (int rr = 0; rr < 64; rr += 2) {
        float a0=0,a1=0,a2=0,a3=0, b0=0,b1=0,b2=0,b3=0;
        const float4* x0 = (const float4*)(xs + rr * DD);
        const float4* x1 = (const float4*)(xs + (rr + 1) * DD);
        #pragma unroll
        for (int k4 = 0; k4 < DD / 4; ++k4) {
            float4 xv = x0[k4], yv = x1[k4];
            a0 = fmaf(xv.x, w[4*k4+0], a0);
            a1 = fmaf(xv.y, w[4*k4+1], a1);
            a2 = fmaf(xv.z, w[4*k4+2], a2);
            a3 = fmaf(xv.w, w[4*k4+3], a3);
            b0 = fmaf(yv.x, w[4*k4+0], b0);
            b1 = fmaf(yv.y, w[4*k4+1], b1);
            b2 = fmaf(yv.z, w[4*k4+2], b2);
            b3 = fmaf(yv.w, w[4*k4+3], b3);
        }
        size_t r = (size_t)rbase + rr;
        z1x[r * 256 + tid]       = (a0 + a1) + (a2 + a3);
        z1x[(r + 1) * 256 + tid] = (b0 + b1) + (b2 + b3);
    }
}

// ================= recurrent kernel: layer-pipelined, 512 threads ============
// Waves 0-3 (gid 0): layer 1 at step n; also compute z2x = h1 @ W2x in phase 2.
// Waves 4-7 (gid 1): layer 2 at step n-1; z2h = h2 @ W2h computed in phase 2.
// amdgpu_waves_per_eu(2,2): grid == 1 block/CU == 2 waves/EU exactly, so clamp
// the RA's occupancy target to 2 -> 256-VGPR budget -> weight arrays stay in
// registers instead of spilling to scratch (R5/R7 post-mortem: backend chose a
// 5-waves/EU budget of ~96 VGPRs and spilled ~128 weight floats per thread).
__global__ __launch_bounds__(512) __attribute__((amdgpu_waves_per_eu(2, 2)))
void lstm_rec(const float* __restrict__ z1x,
              const float* __restrict__ W1, const float* __restrict__ W2,
              const float* __restrict__ gamma1, const float* __restrict__ beta1,
              const float* __restrict__ gc1, const float* __restrict__ bc1,
              const float* __restrict__ gamma2, const float* __restrict__ beta2,
              const float* __restrict__ gc2, const float* __restrict__ bc2,
              const float* __restrict__ Wd, const float* __restrict__ bd,
              float* __restrict__ out, float* __restrict__ state,
              int t0, int nsteps)
{
    const int tid  = threadIdx.x;
    const int b    = blockIdx.x;
    const int gid  = tid >> 8;        // 0 = layer-1 group, 1 = layer-2 group
    const int stid = tid & 255;
    const int lane = stid & 63;
    const int wav  = stid >> 6;

    __shared__ __align__(16) float zsA[256], zsB[256], z2xs[256];
    __shared__ __align__(16) float h1p[4][UU], h2p[4][UU];
    __shared__ __align__(16) float h2hist[16 * 65];
    __shared__ __align__(16) float wds[UU * 16];
    __shared__ float bds[16];

    float* st = state + (size_t)b * 256;

    if (gid == 0) {
        // =========================== LAYER 1 (+ z2x feed) ===================
        float w1h[UU], w2x[UU];
        #pragma unroll
        for (int k = 0; k < UU; ++k) w1h[k] = W1[(DD + k) * 256 + stid];
        #pragma unroll
        for (int k = 0; k < UU; ++k) w2x[k] = W2[k * 256 + stid];
        const float g1 = gamma1[stid], bb1 = beta1[stid];
        const float gcl = gc1[lane],  bcl = bc1[lane];
        for (int i = stid; i < UU * 16; i += 256) wds[i] = Wd[i];
        if (stid < 16) bds[stid] = bd[stid];

        float c1, h1v = 0.f;
        if (t0 == 0) { c1 = 0.f; h1p[wav][lane] = 0.f; }
        else         { c1 = st[lane]; h1v = st[64 + lane]; h1p[wav][lane] = h1v; }

        const float* zrow = z1x + (size_t)b * nsteps * 256;
        float zx = zrow[stid];
        __syncthreads();                       // (init)

        #pragma unroll 1
        for (int n = 0; n <= nsteps; ++n) {
            float zxn = zx;
            if (n < nsteps) {
                int tnl = (n + 1 < nsteps) ? n + 1 : n;
                zxn = zrow[(size_t)tnl * 256 + stid];

                float zdot;
                DOT64(zdot, h1p[wav], w1h);
                float z = zx + zdot;
                float s = wave_red_sum(z);
                float q = wave_red_sum(z * z);
                float mu  = s * (1.f/64.f);
                float var = q * (1.f/64.f) - mu * mu;
                float zn  = (z - mu) * __builtin_amdgcn_rsqf(var + 1e-12f) * g1 + bb1;
                zsA[stid] = (wav == 1) ? tanhfast(zn)
                          : (wav == 2) ? sigm(zn + 1.f)
                          :              sigm(zn);
            }
            // batched output projection for rows t2p-15..t2p (t2p = n-2)
            if ((n & 15) == 1 && n >= 17) {
                int t2p  = n - 2;
                int rloc = stid >> 4;
                int a    = stid & 15;
                float o = bds[a];
                #pragma unroll
                for (int k = 0; k < UU; ++k)
                    o = fmaf(h2hist[rloc * 65 + k], wds[k * 16 + a], o);
                int r = t0 + t2p - 15 + rloc;
                out[((size_t)b * TT + r) * 16 + a] = tanhfast(o);
            }
            __syncthreads();                   // B1
            if (n < nsteps) {
                float ai = zsA[lane],       aj = zsA[64 + lane];
                float af = zsA[128 + lane], ao = zsA[192 + lane];
                c1 = c1 * af + ai * aj;
                float cs = wave_red_sum(c1);
                float cq = wave_red_sum(c1 * c1);
                float cmu  = cs * (1.f/64.f);
                float cvar = cq * (1.f/64.f) - cmu * cmu;
                float cn   = (c1 - cmu) * __builtin_amdgcn_rsqf(cvar + 1e-12f) * gcl + bcl;
                h1v = tanhfast(cn) * ao;
                h1p[wav][lane] = h1v;
                // z2x = h1(n) @ W2x  (own-wave LDS write -> read, no barrier)
                float zxdot;
                DOT64(zxdot, h1p[wav], w2x);
                z2xs[stid] = zxdot;
            }
            __syncthreads();                   // B2
            zx = zxn;
        }
        // final projection: rows nsteps-16..nsteps-1
        {
            int rloc = stid >> 4;
            int a    = stid & 15;
            float o = bds[a];
            #pragma unroll
            for (int k = 0; k < UU; ++k)
                o = fmaf(h2hist[rloc * 65 + k], wds[k * 16 + a], o);
            int r = t0 + nsteps - 16 + rloc;
            out[((size_t)b * TT + r) * 16 + a] = tanhfast(o);
        }
        if (t0 + nsteps < TT && wav == 0) {
            st[lane]      = c1;
            st[64 + lane] = h1v;
        }
    } else {
        // =========================== LAYER 2 ===========================
        float w2h[UU];
        #pragma unroll
        for (int k = 0; k < UU; ++k) w2h[k] = W2[(UU + k) * 256 + stid];
        const float g2 = gamma2[stid], bb2 = beta2[stid];
        const float gcl = gc2[lane],  bcl = bc2[lane];

        float c2, h2v = 0.f;
        if (t0 == 0) { c2 = 0.f; h2p[wav][lane] = 0.f; }
        else         { c2 = st[128 + lane]; h2v = st[192 + lane]; h2p[wav][lane] = h2v; }
        // z2h carried in-register: h2(prev) @ W2h (recomputed at chunk start)
        float z2h = 0.f;
        if (t0 != 0) { DOT64(z2h, h2p[wav], w2h); }
        __syncthreads();                       // (init)

        #pragma unroll 1
        for (int n = 0; n <= nsteps; ++n) {
            if (n >= 1) {
                float z2 = z2xs[stid] + z2h;
                float s2 = wave_red_sum(z2);
                float q2 = wave_red_sum(z2 * z2);
                float mu2  = s2 * (1.f/64.f);
                float var2 = q2 * (1.f/64.f) - mu2 * mu2;
                float zn2  = (z2 - mu2) * __builtin_amdgcn_rsqf(var2 + 1e-12f) * g2 + bb2;
                zsB[stid] = (wav == 1) ? tanhfast(zn2)
                          : (wav == 2) ? sigm(zn2 + 1.f)
                          :              sigm(zn2);
            }
            __syncthreads();                   // B1
            if (n >= 1) {
                float ai = zsB[lane],       aj = zsB[64 + lane];
                float af = zsB[128 + lane], ao = zsB[192 + lane];
                c2 = c2 * af + ai * aj;
                float cs = wave_red_sum(c2);
                float cq = wave_red_sum(c2 * c2);
                float cmu  = cs * (1.f/64.f);
                float cvar = cq * (1.f/64.f) - cmu * cmu;
                float cn   = (c2 - cmu) * __builtin_amdgcn_rsqf(cvar + 1e-12f) * gcl + bcl;
                h2v = tanhfast(cn) * ao;
                h2p[wav][lane] = h2v;
                if (wav == 0) h2hist[((n - 1) & 15) * 65 + lane] = h2v;
                // z2h = h2(n-1) @ W2h for next step (own-wave write->read)
                DOT64(z2h, h2p[wav], w2h);
            }
            __syncthreads();                   // B2
        }
        if (t0 + nsteps < TT && wav == 0) {
            st[128 + lane] = c2;
            st[192 + lane] = h2v;
        }
    }
}

extern "C" void kernel_launch(void* const* d_in, const int* in_sizes, int n_in,
                              void* d_out, int out_size, void* d_ws, size_t ws_size,
                              hipStream_t stream) {
    (void)in_sizes; (void)n_in; (void)out_size;
    const float* obss   = (const float*)d_in[0];
    const float* W1     = (const float*)d_in[1];
    const float* gamma1 = (const float*)d_in[2];
    const float* beta1  = (const float*)d_in[3];
    const float* gc1    = (const float*)d_in[4];
    const float* bc1    = (const float*)d_in[5];
    const float* W2     = (const float*)d_in[6];
    const float* gamma2 = (const float*)d_in[7];
    const float* beta2  = (const float*)d_in[8];
    const float* gc2    = (const float*)d_in[9];
    const float* bc2    = (const float*)d_in[10];
    const float* Wd     = (const float*)d_in[11];
    const float* bd     = (const float*)d_in[12];
    float* out = (float*)d_out;

    float* state = (float*)d_ws;
    float* z1x   = (float*)((char*)d_ws + (size_t)256 * 256 * sizeof(float));

    int CH = 16;
    for (int c = TT; c >= 16; c >>= 1) {
        size_t need = (size_t)256 * c * 256 * sizeof(float)
                    + (size_t)256 * 256 * sizeof(float);
        if (need <= ws_size) { CH = c; break; }
    }
    int chsh = 31 - __builtin_clz((unsigned)CH);

    for (int t0 = 0; t0 < TT; t0 += CH) {
        xgemm<<<(256 * CH) / 64, 256, 0, stream>>>(obss, W1, z1x, t0, chsh);
        lstm_rec<<<256, 512, 0, stream>>>(z1x, W1, W2,
                                          gamma1, beta1, gc1, bc1,
                                          gamma2, beta2, gc2, bc2,
                                          Wd, bd, out, state, t0, CH);
    }
}

// Round 9
// 1348.410 us; speedup vs baseline: 1.5311x; 1.0822x over previous
//
#include <hip/hip_runtime.h>
#include <math.h>

#define TT 1024
#define DD 128
#define UU 64

__device__ __forceinline__ float sigm(float x) {
    return __builtin_amdgcn_rcpf(1.0f + __expf(-x));
}
__device__ __forceinline__ float tanhfast(float x) {
    float e = __expf(2.0f * x);
    return fmaf(-2.0f, __builtin_amdgcn_rcpf(e + 1.0f), 1.0f);
}

// DPP-based full-wave (64-lane) sum, result broadcast via readlane(63).
template<int CTRL>
__device__ __forceinline__ float dpp_add(float v) {
    return v + __int_as_float(__builtin_amdgcn_update_dpp(
        0, __float_as_int(v), CTRL, 0xf, 0xf, true));
}
__device__ __forceinline__ float wave_red_sum(float v) {
    v = dpp_add<0x111>(v);   // row_shr:1
    v = dpp_add<0x112>(v);   // row_shr:2
    v = dpp_add<0x114>(v);   // row_shr:4
    v = dpp_add<0x118>(v);   // row_shr:8
    v = dpp_add<0x142>(v);   // row_bcast:15
    v = dpp_add<0x143>(v);   // row_bcast:31
    return __int_as_float(__builtin_amdgcn_readlane(__float_as_int(v), 63));
}

// 64-float dot: LDS vector (broadcast reads) x register-resident weight ARRAY.
#define DOT64(res, vptr, WARR) do {                                \
    const float4* _v4 = (const float4*)(vptr);                     \
    float _a0 = 0.f, _a1 = 0.f, _a2 = 0.f, _a3 = 0.f;              \
    _Pragma("unroll")                                              \
    for (int _k = 0; _k < UU / 4; ++_k) {                          \
        float4 _hv = _v4[_k];                                      \
        _a0 = fmaf(_hv.x, WARR[4 * _k + 0], _a0);                  \
        _a1 = fmaf(_hv.y, WARR[4 * _k + 1], _a1);                  \
        _a2 = fmaf(_hv.z, WARR[4 * _k + 2], _a2);                  \
        _a3 = fmaf(_hv.w, WARR[4 * _k + 3], _a3);                  \
    }                                                              \
    res = (_a0 + _a1) + (_a2 + _a3);                               \
} while (0)

// ================= x-part GEMM (round-4 proven version) ======================
// z1x[r, col] = obss[b, t0+tloc, :] @ W1[0:128, col]
__global__ __launch_bounds__(256, 1)
void xgemm(const float* __restrict__ obss, const float* __restrict__ W1,
           float* __restrict__ z1x, int t0, int chsh)
{
    const int tid = threadIdx.x;
    const int CH = 1 << chsh;
    __shared__ __align__(16) float xs[64 * DD];

    const int rbase = blockIdx.x * 64;
    for (int i = tid; i < 64 * (DD / 4); i += 256) {
        int rr = i >> 5;
        int k4 = i & 31;
        int r  = rbase + rr;
        int b  = r >> chsh;
        int tl = r & (CH - 1);
        ((float4*)xs)[rr * 32 + k4] =
            ((const float4*)(obss + ((size_t)b * TT + t0 + tl) * DD))[k4];
    }

    float w[DD];
    #pragma unroll
    for (int k = 0; k < DD; ++k) w[k] = W1[k * 256 + tid];
    __syncthreads();

    for (int rr = 0; rr < 64; rr += 2) {
        float a0=0,a1=0,a2=0,a3=0, b0=0,b1=0,b2=0,b3=0;
        const float4* x0 = (const float4*)(xs + rr * DD);
        const float4* x1 = (const float4*)(xs + (rr + 1) * DD);
        #pragma unroll
        for (int k4 = 0; k4 < DD / 4; ++k4) {
            float4 xv = x0[k4], yv = x1[k4];
            a0 = fmaf(xv.x, w[4*k4+0], a0);
            a1 = fmaf(xv.y, w[4*k4+1], a1);
            a2 = fmaf(xv.z, w[4*k4+2], a2);
            a3 = fmaf(xv.w, w[4*k4+3], a3);
            b0 = fmaf(yv.x, w[4*k4+0], b0);
            b1 = fmaf(yv.y, w[4*k4+1], b1);
            b2 = fmaf(yv.z, w[4*k4+2], b2);
            b3 = fmaf(yv.w, w[4*k4+3], b3);
        }
        size_t r = (size_t)rbase + rr;
        z1x[r * 256 + tid]       = (a0 + a1) + (a2 + a3);
        z1x[(r + 1) * 256 + tid] = (b0 + b1) + (b2 + b3);
    }
}

// ============ recurrent kernel: 3-group pipeline, 768 threads ================
// G0 (waves 0-3):  layer 1 at step n.  w1h in registers (64 f32).
// G1 (waves 4-7):  z2x = h1(n-1) @ W2x (p1) + output projection (p2). w2x regs.
// G2 (waves 8-11): layer 2 at step n-2: cell2+z2h-dot in p1, z2-LN in p2. w2h regs.
// Every group needs only ~64 weight f32 + ~35 temps -> under the RA's budget,
// so weights are genuinely register-resident (R5-R8: 128-f32 demands spilled).
// h2 lags h1 by 2 steps; h2hist has 32 slots so projection (rows n-18..n-3)
// never touches the slot being written (row n-2).
__global__ __launch_bounds__(768) __attribute__((amdgpu_waves_per_eu(3, 3)))
void lstm_rec(const float* __restrict__ z1x,
              const float* __restrict__ W1, const float* __restrict__ W2,
              const float* __restrict__ gamma1, const float* __restrict__ beta1,
              const float* __restrict__ gc1, const float* __restrict__ bc1,
              const float* __restrict__ gamma2, const float* __restrict__ beta2,
              const float* __restrict__ gc2, const float* __restrict__ bc2,
              const float* __restrict__ Wd, const float* __restrict__ bd,
              float* __restrict__ out, float* __restrict__ state,
              int t0, int nsteps)
{
    const int tid  = threadIdx.x;
    const int b    = blockIdx.x;
    const int gid  = tid >> 8;        // 0, 1, 2
    const int stid = tid & 255;
    const int lane = stid & 63;
    const int wav  = stid >> 6;

    __shared__ __align__(16) float zsA[256], zsB[256], z2xs[256];
    __shared__ __align__(16) float h1ring[2][UU];
    __shared__ __align__(16) float h1p[4][UU], h2p[4][UU];
    __shared__ __align__(16) float h2hist[32 * 65];
    __shared__ __align__(16) float wds[UU * 16];
    __shared__ float bds[16];

    float* st = state + (size_t)b * 256;
    const int NS = nsteps;

    if (gid == 0) {
        // ============================ G0: LAYER 1 ===========================
        float w1h[UU];
        #pragma unroll
        for (int k = 0; k < UU; ++k) w1h[k] = W1[(DD + k) * 256 + stid];
        const float g1 = gamma1[stid], bb1 = beta1[stid];
        const float gcl = gc1[lane],  bcl = bc1[lane];

        float c1, h1v = 0.f;
        if (t0 == 0) { c1 = 0.f; h1p[wav][lane] = 0.f; }
        else         { c1 = st[lane]; h1v = st[64 + lane]; h1p[wav][lane] = h1v; }

        const float* zrow = z1x + (size_t)b * NS * 256;
        float zx = zrow[stid];
        __syncthreads();                       // init

        #pragma unroll 1
        for (int n = 0; n <= NS + 2; ++n) {
            float zxn = zx;
            if (n < NS) {
                int tnl = (n + 1 < NS) ? n + 1 : n;
                zxn = zrow[(size_t)tnl * 256 + stid];

                float zdot;
                DOT64(zdot, h1p[wav], w1h);
                float z = zx + zdot;
                float s = wave_red_sum(z);
                float q = wave_red_sum(z * z);
                float mu  = s * (1.f/64.f);
                float var = q * (1.f/64.f) - mu * mu;
                float zn  = (z - mu) * __builtin_amdgcn_rsqf(var + 1e-12f) * g1 + bb1;
                zsA[stid] = (wav == 1) ? tanhfast(zn)
                          : (wav == 2) ? sigm(zn + 1.f)
                          :              sigm(zn);
            }
            __syncthreads();                   // B1
            if (n < NS) {
                float ai = zsA[lane],       aj = zsA[64 + lane];
                float af = zsA[128 + lane], ao = zsA[192 + lane];
                c1 = c1 * af + ai * aj;
                float cs = wave_red_sum(c1);
                float cq = wave_red_sum(c1 * c1);
                float cmu  = cs * (1.f/64.f);
                float cvar = cq * (1.f/64.f) - cmu * cmu;
                float cn   = (c1 - cmu) * __builtin_amdgcn_rsqf(cvar + 1e-12f) * gcl + bcl;
                h1v = tanhfast(cn) * ao;
                h1p[wav][lane] = h1v;
                if (wav == 0) h1ring[n & 1][lane] = h1v;
            }
            __syncthreads();                   // B2
            zx = zxn;
        }
        if (t0 + NS < TT && wav == 0) {
            st[lane]      = c1;
            st[64 + lane] = h1v;
        }
    } else if (gid == 1) {
        // ================= G1: z2x feed + output projection =================
        float w2x[UU];
        #pragma unroll
        for (int k = 0; k < UU; ++k) w2x[k] = W2[k * 256 + stid];
        for (int i = stid; i < UU * 16; i += 256) wds[i] = Wd[i];
        if (stid < 16) bds[stid] = bd[stid];
        __syncthreads();                       // init

        #pragma unroll 1
        for (int n = 0; n <= NS + 2; ++n) {
            if (n >= 1 && n <= NS) {
                float zxdot;
                DOT64(zxdot, h1ring[(n - 1) & 1], w2x);
                z2xs[stid] = zxdot;
            }
            __syncthreads();                   // B1
            // projection for rows n-18 .. n-3 (all written by p1(n); slot
            // (n-2)&31 being written this iteration is NOT in the read set)
            if ((n & 15) == 2 && n >= 18) {
                int rloc = stid >> 4;
                int a    = stid & 15;
                int m    = n - 18 + rloc;          // row within chunk
                float o = bds[a];
                const float* hrow = &h2hist[(m & 31) * 65];
                #pragma unroll
                for (int k = 0; k < UU; ++k)
                    o = fmaf(hrow[k], wds[k * 16 + a], o);
                out[((size_t)b * TT + (t0 + m)) * 16 + a] = tanhfast(o);
            }
            __syncthreads();                   // B2
        }
    } else {
        // ============================ G2: LAYER 2 ===========================
        float w2h[UU];
        #pragma unroll
        for (int k = 0; k < UU; ++k) w2h[k] = W2[(UU + k) * 256 + stid];
        const float g2 = gamma2[stid], bb2 = beta2[stid];
        const float gcl = gc2[lane],  bcl = bc2[lane];

        float c2, h2v = 0.f;
        if (t0 == 0) { c2 = 0.f; h2p[wav][lane] = 0.f; }
        else         { c2 = st[128 + lane]; h2v = st[192 + lane]; h2p[wav][lane] = h2v; }
        // z2h = h2(prev)@W2h carried in-register (recomputed at chunk start)
        float z2h = 0.f;
        if (t0 != 0) { DOT64(z2h, h2p[wav], w2h); }
        __syncthreads();                       // init

        #pragma unroll 1
        for (int n = 0; n <= NS + 2; ++n) {
            if (n >= 2 && n <= NS + 1) {
                // cell2 for step n-2 (zsB written p2(n-1), crosses B2)
                float ai = zsB[lane],       aj = zsB[64 + lane];
                float af = zsB[128 + lane], ao = zsB[192 + lane];
                c2 = c2 * af + ai * aj;
                float cs = wave_red_sum(c2);
                float cq = wave_red_sum(c2 * c2);
                float cmu  = cs * (1.f/64.f);
                float cvar = cq * (1.f/64.f) - cmu * cmu;
                float cn   = (c2 - cmu) * __builtin_amdgcn_rsqf(cvar + 1e-12f) * gcl + bcl;
                h2v = tanhfast(cn) * ao;
                h2p[wav][lane] = h2v;
                if (wav == 0) h2hist[((n - 2) & 31) * 65 + lane] = h2v;
                // z2h = h2(n-2) @ W2h for z2(n-1), assembled in p2 this iter
                DOT64(z2h, h2p[wav], w2h);
            }
            __syncthreads();                   // B1
            if (n >= 1 && n <= NS) {
                // z2 for step n-1 (z2xs written G1 p1(n), crosses B1)
                float z2 = z2xs[stid] + z2h;
                float s2 = wave_red_sum(z2);
                float q2 = wave_red_sum(z2 * z2);
                float mu2  = s2 * (1.f/64.f);
                float var2 = q2 * (1.f/64.f) - mu2 * mu2;
                float zn2  = (z2 - mu2) * __builtin_amdgcn_rsqf(var2 + 1e-12f) * g2 + bb2;
                zsB[stid] = (wav == 1) ? tanhfast(zn2)
                          : (wav == 2) ? sigm(zn2 + 1.f)
                          :              sigm(zn2);
            }
            __syncthreads();                   // B2
        }
        if (t0 + NS < TT && wav == 0) {
            st[128 + lane] = c2;
            st[192 + lane] = h2v;
        }
    }
}

extern "C" void kernel_launch(void* const* d_in, const int* in_sizes, int n_in,
                              void* d_out, int out_size, void* d_ws, size_t ws_size,
                              hipStream_t stream) {
    (void)in_sizes; (void)n_in; (void)out_size;
    const float* obss   = (const float*)d_in[0];
    const float* W1     = (const float*)d_in[1];
    const float* gamma1 = (const float*)d_in[2];
    const float* beta1  = (const float*)d_in[3];
    const float* gc1    = (const float*)d_in[4];
    const float* bc1    = (const float*)d_in[5];
    const float* W2     = (const float*)d_in[6];
    const float* gamma2 = (const float*)d_in[7];
    const float* beta2  = (const float*)d_in[8];
    const float* gc2    = (const float*)d_in[9];
    const float* bc2    = (const float*)d_in[10];
    const float* Wd     = (const float*)d_in[11];
    const float* bd     = (const float*)d_in[12];
    float* out = (float*)d_out;

    float* state = (float*)d_ws;
    float* z1x   = (float*)((char*)d_ws + (size_t)256 * 256 * sizeof(float));

    int CH = 16;
    for (int c = TT; c >= 16; c >>= 1) {
        size_t need = (size_t)256 * c * 256 * sizeof(float)
                    + (size_t)256 * 256 * sizeof(float);
        if (need <= ws_size) { CH = c; break; }
    }
    int chsh = 31 - __builtin_clz((unsigned)CH);

    for (int t0 = 0; t0 < TT; t0 += CH) {
        xgemm<<<(256 * CH) / 64, 256, 0, stream>>>(obss, W1, z1x, t0, chsh);
        lstm_rec<<<256, 768, 0, stream>>>(z1x, W1, W2,
                                          gamma1, beta1, gc1, bc1,
                                          gamma2, beta2, gc2, bc2,
                                          Wd, bd, out, state, t0, CH);
    }
}